// Round 9
// baseline (110.626 us; speedup 1.0000x reference)
//
#include <hip/hip_runtime.h>

#define NK 21      // classes
#define NC 256     // channels
#define NSRC 64    // source h/w
#define NOUT 256   // mask h/w
#define NB 8       // batch
#define EPS 1e-6f

// Native LDS fp32 atomic add (ds_add_f32). Plain atomicAdd(float*) lowers to
// a CAS loop — that was the invariant ~44us in R4/R5.
__device__ __forceinline__ void lds_fadd(float* p, float v) {
  __hip_atomic_fetch_add(p, v, __ATOMIC_RELAXED, __HIP_MEMORY_SCOPE_WORKGROUP);
}

// Native global fp32 atomic add (global_atomic_add_f32, fire-and-forget,
// agent scope). Avoids both the CAS lowering AND the 22-44 MB psum HBM
// round-trip that dominated R6-R8's controllable cost.
__device__ __forceinline__ void glb_fadd(float* p, float v) {
  __hip_atomic_fetch_add(p, v, __ATOMIC_RELAXED, __HIP_MEMORY_SCOPE_AGENT);
}

// ---------------------------------------------------------------------------
// Main kernel. Grid (64, NB, 2): (source row r0, image b, column-half z).
// R7's proven phases; only the epilogue changes: atomic accumulation into
// L2-resident psum[B][K][C] (172 KB) instead of 22 MB of spilled partials.
// ---------------------------------------------------------------------------
__global__ __launch_bounds__(256, 4)
void proto_main(const float* __restrict__ feats,
                const int* __restrict__ masks,
                float* __restrict__ psum,   // [B][K][C]  (zeroed, atomic)
                float* __restrict__ pcnt) { // [B][K]     (zeroed, atomic)
  __shared__ __align__(16) float Wl[NK * 32];
  __shared__ int hist[NK];

  const int tid = threadIdx.x;
  const int r0 = blockIdx.x;  // source row 0..63
  const int b = blockIdx.y;   // image
  const int z = blockIdx.z;   // column half 0/1

  // ---- Phase 0: early feats prefetch (named regs) ----
  const float4* fbase = (const float4*)(
      feats + ((size_t)(b * NC + tid) << 12) + (size_t)r0 * 64 + 32 * z);
  const float4 f0 = fbase[0], f1 = fbase[1], f2 = fbase[2], f3 = fbase[3];
  const float4 f4 = fbase[4], f5 = fbase[5], f6 = fbase[6], f7 = fbase[7];

  for (int i = tid; i < NK * 32; i += 256) Wl[i] = 0.f;
  if (tid < NK) hist[tid] = 0;
  __syncthreads();

  // ---- Phase 1 ----
  int ylo = 4 * r0 - 2; if (ylo < 0) ylo = 0;
  int yhi = 4 * r0 + 5; if (yhi > NOUT - 1) yhi = NOUT - 1;
  const int xlo = z ? 126 : 0;  // 130-wide window covers all taps of this half
  const int npix = (yhi - ylo + 1) * 130;
  const int own_lo = 4 * r0;    // count ownership: y in [4r0,4r0+4), x-half z

  for (int i = tid; i < npix; i += 256) {
    const int x = xlo + i % 130;
    const int y = ylo + i / 130;
    const int lbl = masks[((size_t)b * NOUT + y) * NOUT + x];
    if ((unsigned)lbl < NK) {
      // src = 0.25*t - 0.375 (half-pixel 4x); taps j0, j0+1, clamped
      const int ry = y >> 2, py = y & 3;
      const int j0y = (py < 2) ? ry - 1 : ry;
      const float fy = (py == 0) ? 0.625f : (py == 1) ? 0.875f
                     : (py == 2) ? 0.125f : 0.375f;
      const int rx = x >> 2, px = x & 3;
      const int j0x = (px < 2) ? rx - 1 : rx;
      const float fx = (px == 0) ? 0.625f : (px == 1) ? 0.875f
                     : (px == 2) ? 0.125f : 0.375f;

      const int cx0 = (j0x < 0) ? 0 : j0x;
      const int cx1 = (j0x + 1 > NSRC - 1) ? NSRC - 1 : j0x + 1;
      const float wx0 = 1.f - fx, wx1 = fx;
      const int ry0 = (j0y < 0) ? 0 : j0y;
      const int ry1 = (j0y + 1 > NSRC - 1) ? NSRC - 1 : j0y + 1;
      const float wy0 = 1.f - fy, wy1 = fy;

      float* Wk = &Wl[lbl * 32];
      if (ry0 == r0) {
        if ((cx0 >> 5) == z) lds_fadd(&Wk[cx0 & 31], wy0 * wx0);
        if ((cx1 >> 5) == z) lds_fadd(&Wk[cx1 & 31], wy0 * wx1);
      }
      if (ry1 == r0) {
        if ((cx0 >> 5) == z) lds_fadd(&Wk[cx0 & 31], wy1 * wx0);
        if ((cx1 >> 5) == z) lds_fadd(&Wk[cx1 & 31], wy1 * wx1);
      }
      if (y >= own_lo && y < own_lo + 4 && (x >> 7) == z)
        atomicAdd(&hist[lbl], 1);  // int: native ds_add
    }
  }
  __syncthreads();

  // ---- Phase 2: acc[k] = sum_s W[k][s] * F[s] ----
  float acc[NK];
#pragma unroll
  for (int k = 0; k < NK; ++k) acc[k] = 0.f;

  const float4* wb = (const float4*)Wl;
#pragma unroll
  for (int k = 0; k < NK; ++k) {  // s 0..15
    const float4 w0 = wb[k * 8 + 0], w1 = wb[k * 8 + 1];
    const float4 w2 = wb[k * 8 + 2], w3 = wb[k * 8 + 3];
    float a = acc[k];
    a = fmaf(f0.x, w0.x, a); a = fmaf(f0.y, w0.y, a);
    a = fmaf(f0.z, w0.z, a); a = fmaf(f0.w, w0.w, a);
    a = fmaf(f1.x, w1.x, a); a = fmaf(f1.y, w1.y, a);
    a = fmaf(f1.z, w1.z, a); a = fmaf(f1.w, w1.w, a);
    a = fmaf(f2.x, w2.x, a); a = fmaf(f2.y, w2.y, a);
    a = fmaf(f2.z, w2.z, a); a = fmaf(f2.w, w2.w, a);
    a = fmaf(f3.x, w3.x, a); a = fmaf(f3.y, w3.y, a);
    a = fmaf(f3.z, w3.z, a); a = fmaf(f3.w, w3.w, a);
    acc[k] = a;
  }
#pragma unroll
  for (int k = 0; k < NK; ++k) {  // s 16..31
    const float4 w4 = wb[k * 8 + 4], w5 = wb[k * 8 + 5];
    const float4 w6 = wb[k * 8 + 6], w7 = wb[k * 8 + 7];
    float a = acc[k];
    a = fmaf(f4.x, w4.x, a); a = fmaf(f4.y, w4.y, a);
    a = fmaf(f4.z, w4.z, a); a = fmaf(f4.w, w4.w, a);
    a = fmaf(f5.x, w5.x, a); a = fmaf(f5.y, w5.y, a);
    a = fmaf(f5.z, w5.z, a); a = fmaf(f5.w, w5.w, a);
    a = fmaf(f6.x, w6.x, a); a = fmaf(f6.y, w6.y, a);
    a = fmaf(f6.z, w6.z, a); a = fmaf(f6.w, w6.w, a);
    a = fmaf(f7.x, w7.x, a); a = fmaf(f7.y, w7.y, a);
    a = fmaf(f7.z, w7.z, a); a = fmaf(f7.w, w7.w, a);
    acc[k] = a;
  }

  // ---- Epilogue: native fire-and-forget atomics into L2-resident psum ----
  // 21 x 64-lane-contiguous atomic dwords per wave (4 lines each), 5.5M total.
#pragma unroll
  for (int k = 0; k < NK; ++k)
    glb_fadd(&psum[((size_t)b * NK + k) * NC + tid], acc[k]);
  if (tid < NK) glb_fadd(&pcnt[(size_t)b * NK + tid], (float)hist[tid]);
}

// ---------------------------------------------------------------------------
// Finalize: grid (NK); 172 KB L2-hot.
// out[k][c] = (1/8) sum_b psum[b][k][c] / (pcnt[b][k] + eps)
// ---------------------------------------------------------------------------
__global__ __launch_bounds__(256)
void proto_final(const float* __restrict__ psum,
                 const float* __restrict__ pcnt,
                 float* __restrict__ out) {
  const int k = blockIdx.x;   // 0..20
  const int c = threadIdx.x;  // 0..255
  float a = 0.f;
#pragma unroll
  for (int b = 0; b < NB; ++b)
    a += psum[((size_t)b * NK + k) * NC + c] / (pcnt[(size_t)b * NK + k] + EPS);
  out[(size_t)k * NC + c] = a * 0.125f;
}

extern "C" void kernel_launch(void* const* d_in, const int* in_sizes, int n_in,
                              void* d_out, int out_size, void* d_ws, size_t ws_size,
                              hipStream_t stream) {
  const float* feats = (const float*)d_in[0];
  const int* masks = (const int*)d_in[1];
  float* out = (float*)d_out;

  // ws: psum [8][21][256] (172 KB) | pcnt [8][21] (672 B) — L2-resident.
  float* psum = (float*)d_ws;
  float* pcnt = psum + (size_t)NB * NK * NC;
  const size_t zbytes = ((size_t)NB * NK * NC + (size_t)NB * NK) * 4;

  hipMemsetAsync(d_ws, 0, zbytes, stream);
  proto_main<<<dim3(64, NB, 2), 256, 0, stream>>>(feats, masks, psum, pcnt);
  proto_final<<<dim3(NK), 256, 0, stream>>>(psum, pcnt, out);
}

// Round 10
// 107.606 us; speedup vs baseline: 1.0281x; 1.0281x over previous
//
#include <hip/hip_runtime.h>

#define NK 21      // classes
#define NC 256     // channels
#define NSRC 64    // source h/w
#define NOUT 256   // mask h/w
#define NB 8       // batch
#define NG 8       // finalA row-groups (8 rows each)
#define EPS 1e-6f

// Native LDS fp32 atomic add (ds_add_f32). Plain atomicAdd(float*) is a CAS
// loop (R4/R5 lesson). Global fp32 atomics are fabric-rate-limited at
// ~125 G/s regardless of scope (R9 lesson) — never use them in bulk.
__device__ __forceinline__ void lds_fadd(float* p, float v) {
  __hip_atomic_fetch_add(p, v, __ATOMIC_RELAXED, __HIP_MEMORY_SCOPE_WORKGROUP);
}

// ---------------------------------------------------------------------------
// Kernel A (scatter): grid (64, NB). Build the bilinear-adjoint weight map
// W[21][64] for source row r0 in LDS, plus per-class pixel counts, then dump
// both to global. Tiny kernel: ~2K LDS-pipe cycles + 2 MB mask reads.
// ---------------------------------------------------------------------------
__global__ __launch_bounds__(256)
void proto_scatter(const int* __restrict__ masks,
                   float* __restrict__ Wg,     // [B][64][NK][64]
                   float* __restrict__ pcnt) { // [B][64][NK]
  __shared__ float Wl[NK * 64];
  __shared__ int hist[NK];

  const int tid = threadIdx.x;
  const int r0 = blockIdx.x;  // source row 0..63
  const int b = blockIdx.y;   // image

  for (int i = tid; i < NK * 64; i += 256) Wl[i] = 0.f;
  if (tid < NK) hist[tid] = 0;
  __syncthreads();

  int ylo = 4 * r0 - 2; if (ylo < 0) ylo = 0;
  int yhi = 4 * r0 + 5; if (yhi > NOUT - 1) yhi = NOUT - 1;
  const int npix = (yhi - ylo + 1) * NOUT;
  const int own_lo = 4 * r0;  // count ownership: y in [4r0, 4r0+4)

  for (int i = tid; i < npix; i += 256) {
    const int x = i & (NOUT - 1);
    const int y = ylo + (i >> 8);
    const int lbl = masks[((size_t)b * NOUT + y) * NOUT + x];
    if ((unsigned)lbl < NK) {
      // src = 0.25*t - 0.375 (half-pixel 4x); taps j0, j0+1, clamped
      const int ry = y >> 2, py = y & 3;
      const int j0y = (py < 2) ? ry - 1 : ry;
      const float fy = (py == 0) ? 0.625f : (py == 1) ? 0.875f
                     : (py == 2) ? 0.125f : 0.375f;
      const int rx = x >> 2, px = x & 3;
      const int j0x = (px < 2) ? rx - 1 : rx;
      const float fx = (px == 0) ? 0.625f : (px == 1) ? 0.875f
                     : (px == 2) ? 0.125f : 0.375f;

      const int cx0 = (j0x < 0) ? 0 : j0x;
      const int cx1 = (j0x + 1 > NSRC - 1) ? NSRC - 1 : j0x + 1;
      const float wx0 = 1.f - fx, wx1 = fx;
      const int ry0 = (j0y < 0) ? 0 : j0y;
      const int ry1 = (j0y + 1 > NSRC - 1) ? NSRC - 1 : j0y + 1;
      const float wy0 = 1.f - fy, wy1 = fy;

      float* Wk = &Wl[lbl * 64];
      if (ry0 == r0) {
        lds_fadd(&Wk[cx0], wy0 * wx0);
        lds_fadd(&Wk[cx1], wy0 * wx1);
      }
      if (ry1 == r0) {
        lds_fadd(&Wk[cx0], wy1 * wx0);
        lds_fadd(&Wk[cx1], wy1 * wx1);
      }
      if (y >= own_lo && y < own_lo + 4) atomicAdd(&hist[lbl], 1);
    }
  }
  __syncthreads();

  // Dump W + counts to global (coalesced dword stores).
  float* wdst = Wg + (size_t)(b * 64 + r0) * (NK * 64);
  for (int i = tid; i < NK * 64; i += 256) wdst[i] = Wl[i];
  if (tid < NK) pcnt[(size_t)(b * 64 + r0) * NK + tid] = (float)hist[tid];
}

// ---------------------------------------------------------------------------
// Kernel B (apply): grid (64, NB); thread = channel. ZERO LDS USE — the W
// row is wave-uniform, read via the SCALAR path (s_load into SGPRs, FMA with
// SGPR operand). R7's main spent ~13.5us/CU on 168 broadcast ds_read_b128
// per wave; the scalar pipe removes that entirely.
// ---------------------------------------------------------------------------
__global__ __launch_bounds__(256, 4)
void proto_apply(const float* __restrict__ feats,
                 const float* __restrict__ Wg,
                 float* __restrict__ psum) {  // [B][64][NK][NC]
  const int tid = threadIdx.x;  // channel
  const int r0 = blockIdx.x;
  const int b = blockIdx.y;

  // Wave-uniform W base — readfirstlane pins it in SGPRs so the 336 W
  // float4 reads lower to s_load (scalar cache), not per-lane VMEM.
  const int woff4 = __builtin_amdgcn_readfirstlane((b * 64 + r0) * (NK * 16));
  const float4* __restrict__ w4 = (const float4*)Wg + woff4;

  const float4* fbase =
      (const float4*)(feats + ((size_t)(b * NC + tid) << 12) + (size_t)r0 * 64);
  float4 f[16];
#pragma unroll
  for (int j = 0; j < 16; ++j) f[j] = fbase[j];  // 16 loads in flight, 1 line/lane

  float acc[NK];
#pragma unroll
  for (int k = 0; k < NK; ++k) {
    const float4* wk = w4 + k * 16;
    float a = 0.f;
#pragma unroll
    for (int j = 0; j < 16; ++j) {
      const float4 w = wk[j];  // uniform -> s_load_dwordx4
      a = fmaf(f[j].x, w.x, a);
      a = fmaf(f[j].y, w.y, a);
      a = fmaf(f[j].z, w.z, a);
      a = fmaf(f[j].w, w.w, a);
    }
    acc[k] = a;
  }

  float* dst = psum + ((size_t)(b * 64 + r0) * NK) * NC + tid;
#pragma unroll
  for (int k = 0; k < NK; ++k) dst[k * NC] = acc[k];  // coalesced
}

// ---------------------------------------------------------------------------
// Finalize A: grid (NK, NB, NG); each block reduces 8 rows.
// ---------------------------------------------------------------------------
__global__ __launch_bounds__(256)
void proto_finalA(const float* __restrict__ psum,
                  const float* __restrict__ pcnt,
                  float* __restrict__ psum2,   // [B][NG][NK][NC]
                  float* __restrict__ pcnt2) { // [B][NG][NK]
  const int k = blockIdx.x;
  const int b = blockIdx.y;
  const int g = blockIdx.z;
  const int c = threadIdx.x;
  const int r0 = g * 8;
  float s = 0.f, cnt = 0.f;
#pragma unroll
  for (int j = 0; j < 8; ++j) {
    s += psum[((size_t)(b * 64 + r0 + j) * NK + k) * NC + c];  // coalesced
    cnt += pcnt[(size_t)(b * 64 + r0 + j) * NK + k];           // uniform
  }
  psum2[((size_t)(b * NG + g) * NK + k) * NC + c] = s;
  if (c == 0) pcnt2[(size_t)(b * NG + g) * NK + k] = cnt;
}

// ---------------------------------------------------------------------------
// Finalize B: grid (NK); L2-hot 1.4 MB.
// out[k][c] = (1/8) sum_b [sum_g psum2] / (sum_g pcnt2 + eps)
// ---------------------------------------------------------------------------
__global__ __launch_bounds__(256)
void proto_finalB(const float* __restrict__ psum2,
                  const float* __restrict__ pcnt2,
                  float* __restrict__ out) {
  const int k = blockIdx.x;
  const int c = threadIdx.x;
  float a = 0.f;
#pragma unroll
  for (int b = 0; b < NB; ++b) {
    float s = 0.f, cnt = 0.f;
#pragma unroll
    for (int g = 0; g < NG; ++g) {
      s += psum2[((size_t)(b * NG + g) * NK + k) * NC + c];
      cnt += pcnt2[(size_t)(b * NG + g) * NK + k];
    }
    a += s / (cnt + EPS);
  }
  out[(size_t)k * NC + c] = a * 0.125f;
}

extern "C" void kernel_launch(void* const* d_in, const int* in_sizes, int n_in,
                              void* d_out, int out_size, void* d_ws, size_t ws_size,
                              hipStream_t stream) {
  const float* feats = (const float*)d_in[0];
  const int* masks = (const int*)d_in[1];
  float* out = (float*)d_out;

  // ws: Wg [8][64][21][64] (5.5 MB) | psum [8][64][21][256] (22 MB)
  //   | pcnt [8][64][21] (43 KB)    | psum2 [8][8][21][256] (1.4 MB)
  //   | pcnt2 [8][8][21] (5.4 KB).  All fully written before read; no memset.
  float* Wg = (float*)d_ws;
  float* psum = Wg + (size_t)NB * 64 * NK * 64;
  float* pcnt = psum + (size_t)NB * 64 * NK * NC;
  float* psum2 = pcnt + (size_t)NB * 64 * NK;
  float* pcnt2 = psum2 + (size_t)NB * NG * NK * NC;

  proto_scatter<<<dim3(64, NB), 256, 0, stream>>>(masks, Wg, pcnt);
  proto_apply<<<dim3(64, NB), 256, 0, stream>>>(feats, Wg, psum);
  proto_finalA<<<dim3(NK, NB, NG), 256, 0, stream>>>(psum, pcnt, psum2, pcnt2);
  proto_finalB<<<dim3(NK), 256, 0, stream>>>(psum2, pcnt2, out);
}

// Round 11
// 102.861 us; speedup vs baseline: 1.0755x; 1.0461x over previous
//
#include <hip/hip_runtime.h>

#define NK 21      // classes
#define NC 256     // channels
#define NSRC 64    // source h/w
#define NOUT 256   // mask h/w
#define NB 8       // batch
#define NSL 128    // producer slices per image: 64 rows x 2 column-halves
#define EPS 1e-6f

// Native LDS fp32 atomic add (ds_add_f32). Plain atomicAdd(float*) is a CAS
// loop (R4/R5). Global fp32 atomics hit a ~125 G/s fabric wall (R9) — fine
// for 43K ops in finalize, fatal for millions.
__device__ __forceinline__ void lds_fadd(float* p, float v) {
  __hip_atomic_fetch_add(p, v, __ATOMIC_RELAXED, __HIP_MEMORY_SCOPE_WORKGROUP);
}
__device__ __forceinline__ void glb_fadd(float* p, float v) {
  __hip_atomic_fetch_add(p, v, __ATOMIC_RELAXED, __HIP_MEMORY_SCOPE_AGENT);
}

// ---------------------------------------------------------------------------
// Main kernel. Grid (64, NB, 2), 128 THREADS: (source row r0, image b,
// column-half z). Each thread computes TWO channels (tid, tid+128) against a
// single W read — halves per-CU LDS-broadcast traffic (R7's main spent ~13us
// of its 22 on the LDS pipe: threads x 2688 B of ds_read_b128 per block).
// Phase 2 stores per-k immediately: live set ~110 VGPR < 128 cap.
// ---------------------------------------------------------------------------
__global__ __launch_bounds__(128, 4)
void proto_main(const float* __restrict__ feats,
                const int* __restrict__ masks,
                float* __restrict__ psum,   // [B][NSL][K][C]
                float* __restrict__ pcnt,   // [B][NSL][K]
                float* __restrict__ out) {  // zeroed here (block 0)
  __shared__ __align__(16) float Wl[NK * 32];
  __shared__ int hist[NK];

  const int tid = threadIdx.x;  // 0..127
  const int r0 = blockIdx.x;    // source row 0..63
  const int b = blockIdx.y;     // image
  const int z = blockIdx.z;     // column half 0/1

  // ---- Phase 0: early feats prefetch for both channels (named regs) ----
  const float4* fb0 = (const float4*)(
      feats + ((size_t)(b * NC + tid) << 12) + (size_t)r0 * 64 + 32 * z);
  const float4* fb1 = (const float4*)(
      feats + ((size_t)(b * NC + tid + 128) << 12) + (size_t)r0 * 64 + 32 * z);
  const float4 f0 = fb0[0], f1 = fb0[1], f2 = fb0[2], f3 = fb0[3];
  const float4 f4 = fb0[4], f5 = fb0[5], f6 = fb0[6], f7 = fb0[7];
  const float4 g0 = fb1[0], g1 = fb1[1], g2 = fb1[2], g3 = fb1[3];
  const float4 g4 = fb1[4], g5 = fb1[5], g6 = fb1[6], g7 = fb1[7];

  // Zero d_out once per launch (final depends on this kernel -> ordered).
  if (r0 == 0 && b == 0 && z == 0)
    for (int i = tid; i < NK * NC; i += 128) out[i] = 0.f;

  for (int i = tid; i < NK * 32; i += 128) Wl[i] = 0.f;
  if (tid < NK) hist[tid] = 0;
  __syncthreads();

  // ---- Phase 1 (R7-proven) ----
  int ylo = 4 * r0 - 2; if (ylo < 0) ylo = 0;
  int yhi = 4 * r0 + 5; if (yhi > NOUT - 1) yhi = NOUT - 1;
  const int xlo = z ? 126 : 0;  // 130-wide window covers all taps of this half
  const int npix = (yhi - ylo + 1) * 130;
  const int own_lo = 4 * r0;    // count ownership: y in [4r0,4r0+4), x-half z

  for (int i = tid; i < npix; i += 128) {
    const int x = xlo + i % 130;
    const int y = ylo + i / 130;
    const int lbl = masks[((size_t)b * NOUT + y) * NOUT + x];
    if ((unsigned)lbl < NK) {
      // src = 0.25*t - 0.375 (half-pixel 4x); taps j0, j0+1, clamped
      const int ry = y >> 2, py = y & 3;
      const int j0y = (py < 2) ? ry - 1 : ry;
      const float fy = (py == 0) ? 0.625f : (py == 1) ? 0.875f
                     : (py == 2) ? 0.125f : 0.375f;
      const int rx = x >> 2, px = x & 3;
      const int j0x = (px < 2) ? rx - 1 : rx;
      const float fx = (px == 0) ? 0.625f : (px == 1) ? 0.875f
                     : (px == 2) ? 0.125f : 0.375f;

      const int cx0 = (j0x < 0) ? 0 : j0x;
      const int cx1 = (j0x + 1 > NSRC - 1) ? NSRC - 1 : j0x + 1;
      const float wx0 = 1.f - fx, wx1 = fx;
      const int ry0 = (j0y < 0) ? 0 : j0y;
      const int ry1 = (j0y + 1 > NSRC - 1) ? NSRC - 1 : j0y + 1;
      const float wy0 = 1.f - fy, wy1 = fy;

      float* Wk = &Wl[lbl * 32];
      if (ry0 == r0) {
        if ((cx0 >> 5) == z) lds_fadd(&Wk[cx0 & 31], wy0 * wx0);
        if ((cx1 >> 5) == z) lds_fadd(&Wk[cx1 & 31], wy0 * wx1);
      }
      if (ry1 == r0) {
        if ((cx0 >> 5) == z) lds_fadd(&Wk[cx0 & 31], wy1 * wx0);
        if ((cx1 >> 5) == z) lds_fadd(&Wk[cx1 & 31], wy1 * wx1);
      }
      if (y >= own_lo && y < own_lo + 4 && (x >> 7) == z)
        atomicAdd(&hist[lbl], 1);  // int: native ds_add
    }
  }
  __syncthreads();

  // ---- Phase 2: per k, one W read serves BOTH channels; store immediately.
  const int sl = r0 * 2 + z;
  float* dst = psum + ((size_t)(b * NSL + sl) * NK) * NC;
  const float4* wb = (const float4*)Wl;
#pragma unroll
  for (int k = 0; k < NK; ++k) {
    const float4 w0 = wb[k * 8 + 0], w1 = wb[k * 8 + 1];
    const float4 w2 = wb[k * 8 + 2], w3 = wb[k * 8 + 3];
    const float4 w4 = wb[k * 8 + 4], w5 = wb[k * 8 + 5];
    const float4 w6 = wb[k * 8 + 6], w7 = wb[k * 8 + 7];
    float a0 = 0.f, a1 = 0.f;
    a0 = fmaf(f0.x, w0.x, a0); a0 = fmaf(f0.y, w0.y, a0);
    a0 = fmaf(f0.z, w0.z, a0); a0 = fmaf(f0.w, w0.w, a0);
    a0 = fmaf(f1.x, w1.x, a0); a0 = fmaf(f1.y, w1.y, a0);
    a0 = fmaf(f1.z, w1.z, a0); a0 = fmaf(f1.w, w1.w, a0);
    a0 = fmaf(f2.x, w2.x, a0); a0 = fmaf(f2.y, w2.y, a0);
    a0 = fmaf(f2.z, w2.z, a0); a0 = fmaf(f2.w, w2.w, a0);
    a0 = fmaf(f3.x, w3.x, a0); a0 = fmaf(f3.y, w3.y, a0);
    a0 = fmaf(f3.z, w3.z, a0); a0 = fmaf(f3.w, w3.w, a0);
    a0 = fmaf(f4.x, w4.x, a0); a0 = fmaf(f4.y, w4.y, a0);
    a0 = fmaf(f4.z, w4.z, a0); a0 = fmaf(f4.w, w4.w, a0);
    a0 = fmaf(f5.x, w5.x, a0); a0 = fmaf(f5.y, w5.y, a0);
    a0 = fmaf(f5.z, w5.z, a0); a0 = fmaf(f5.w, w5.w, a0);
    a0 = fmaf(f6.x, w6.x, a0); a0 = fmaf(f6.y, w6.y, a0);
    a0 = fmaf(f6.z, w6.z, a0); a0 = fmaf(f6.w, w6.w, a0);
    a0 = fmaf(f7.x, w7.x, a0); a0 = fmaf(f7.y, w7.y, a0);
    a0 = fmaf(f7.z, w7.z, a0); a0 = fmaf(f7.w, w7.w, a0);
    a1 = fmaf(g0.x, w0.x, a1); a1 = fmaf(g0.y, w0.y, a1);
    a1 = fmaf(g0.z, w0.z, a1); a1 = fmaf(g0.w, w0.w, a1);
    a1 = fmaf(g1.x, w1.x, a1); a1 = fmaf(g1.y, w1.y, a1);
    a1 = fmaf(g1.z, w1.z, a1); a1 = fmaf(g1.w, w1.w, a1);
    a1 = fmaf(g2.x, w2.x, a1); a1 = fmaf(g2.y, w2.y, a1);
    a1 = fmaf(g2.z, w2.z, a1); a1 = fmaf(g2.w, w2.w, a1);
    a1 = fmaf(g3.x, w3.x, a1); a1 = fmaf(g3.y, w3.y, a1);
    a1 = fmaf(g3.z, w3.z, a1); a1 = fmaf(g3.w, w3.w, a1);
    a1 = fmaf(g4.x, w4.x, a1); a1 = fmaf(g4.y, w4.y, a1);
    a1 = fmaf(g4.z, w4.z, a1); a1 = fmaf(g4.w, w4.w, a1);
    a1 = fmaf(g5.x, w5.x, a1); a1 = fmaf(g5.y, w5.y, a1);
    a1 = fmaf(g5.z, w5.z, a1); a1 = fmaf(g5.w, w5.w, a1);
    a1 = fmaf(g6.x, w6.x, a1); a1 = fmaf(g6.y, w6.y, a1);
    a1 = fmaf(g6.z, w6.z, a1); a1 = fmaf(g6.w, w6.w, a1);
    a1 = fmaf(g7.x, w7.x, a1); a1 = fmaf(g7.y, w7.y, a1);
    a1 = fmaf(g7.z, w7.z, a1); a1 = fmaf(g7.w, w7.w, a1);
    dst[k * NC + tid] = a0;          // coalesced 128-lane pair
    dst[k * NC + tid + 128] = a1;
  }
  if (tid < NK) pcnt[(size_t)(b * NSL + sl) * NK + tid] = (float)hist[tid];
}

// ---------------------------------------------------------------------------
// Finalize: grid (NK, NB) = 168 blocks; reduce all 128 slices (psum is
// L2-resident, 22 MB ~ aggregate L2), then ONE atomic per (k,c,b) into out
// (43K atomics — trivial at the 125 G/s wall). out pre-zeroed by main.
// ---------------------------------------------------------------------------
__global__ __launch_bounds__(256)
void proto_final(const float* __restrict__ psum,
                 const float* __restrict__ pcnt,
                 float* __restrict__ out) {
  const int k = blockIdx.x;   // 0..20
  const int b = blockIdx.y;   // 0..7
  const int c = threadIdx.x;  // 0..255
  float s0 = 0.f, s1 = 0.f, s2 = 0.f, s3 = 0.f, cnt = 0.f;
#pragma unroll
  for (int sl = 0; sl < NSL; sl += 4) {
    s0 += psum[((size_t)(b * NSL + sl + 0) * NK + k) * NC + c];
    s1 += psum[((size_t)(b * NSL + sl + 1) * NK + k) * NC + c];
    s2 += psum[((size_t)(b * NSL + sl + 2) * NK + k) * NC + c];
    s3 += psum[((size_t)(b * NSL + sl + 3) * NK + k) * NC + c];
    cnt += pcnt[(size_t)(b * NSL + sl + 0) * NK + k];
    cnt += pcnt[(size_t)(b * NSL + sl + 1) * NK + k];
    cnt += pcnt[(size_t)(b * NSL + sl + 2) * NK + k];
    cnt += pcnt[(size_t)(b * NSL + sl + 3) * NK + k];
  }
  const float v = ((s0 + s1) + (s2 + s3)) / (cnt + EPS) * 0.125f;
  glb_fadd(&out[k * NC + c], v);
}

extern "C" void kernel_launch(void* const* d_in, const int* in_sizes, int n_in,
                              void* d_out, int out_size, void* d_ws, size_t ws_size,
                              hipStream_t stream) {
  const float* feats = (const float*)d_in[0];
  const int* masks = (const int*)d_in[1];
  float* out = (float*)d_out;

  // ws: psum [8][128][21][256] (22 MB) | pcnt [8][128][21] (86 KB).
  // Fully written before read; no memsets; 2 graph nodes total.
  float* psum = (float*)d_ws;
  float* pcnt = psum + (size_t)NB * NSL * NK * NC;

  proto_main<<<dim3(64, NB, 2), 128, 0, stream>>>(feats, masks, psum, pcnt, out);
  proto_final<<<dim3(NK, NB), 256, 0, stream>>>(psum, pcnt, out);
}

// Round 12
// 102.250 us; speedup vs baseline: 1.0819x; 1.0060x over previous
//
#include <hip/hip_runtime.h>

#define NK 21      // classes
#define NC 256     // channels
#define NSRC 64    // source h/w
#define NOUT 256   // mask h/w
#define NB 8       // batch
#define NSL 128    // producer slices per image: 64 rows x 2 column-halves
#define EPS 1e-6f

// Native LDS fp32 atomic add (ds_add_f32). Plain atomicAdd(float*) is a CAS
// loop (R4/R5). Global fp32 atomics hit a ~125 G/s fabric wall (R9) — fine
// for 43K ops in finalize, fatal for millions.
__device__ __forceinline__ void lds_fadd(float* p, float v) {
  __hip_atomic_fetch_add(p, v, __ATOMIC_RELAXED, __HIP_MEMORY_SCOPE_WORKGROUP);
}
__device__ __forceinline__ void glb_fadd(float* p, float v) {
  __hip_atomic_fetch_add(p, v, __ATOMIC_RELAXED, __HIP_MEMORY_SCOPE_AGENT);
}

// ---------------------------------------------------------------------------
// Main kernel (R7 structure, one fix). Grid (64, NB, 2), 256 threads.
// KEY CHANGE vs R7: the feats prefetch is issued AFTER the first
// __syncthreads. __syncthreads lowers to s_waitcnt vmcnt(0) + s_barrier, so
// R7's "early" prefetch (issued before barrier 1) was fully drained before
// phase 1 started — pure serialized stall. Issued here, the loads stay in
// flight through all of phase 1 and drain at barrier 2, where they're needed.
// ---------------------------------------------------------------------------
__global__ __launch_bounds__(256, 4)
void proto_main(const float* __restrict__ feats,
                const int* __restrict__ masks,
                float* __restrict__ psum,   // [B][NSL][K][C]
                float* __restrict__ pcnt,   // [B][NSL][K]
                float* __restrict__ out) {  // zeroed here (block 0)
  __shared__ __align__(16) float Wl[NK * 32];
  __shared__ int hist[NK];

  const int tid = threadIdx.x;
  const int r0 = blockIdx.x;  // source row 0..63
  const int b = blockIdx.y;   // image
  const int z = blockIdx.z;   // column half 0/1

  for (int i = tid; i < NK * 32; i += 256) Wl[i] = 0.f;
  if (tid < NK) hist[tid] = 0;
  if (r0 == 0 && b == 0 && z == 0)  // zero d_out (final is graph-ordered after)
    for (int i = tid; i < NK * NC; i += 256) out[i] = 0.f;
  __syncthreads();  // drains only the LDS zero-init + out stores

  // ---- Feats prefetch: issued NOW so the 16 loads fly during phase 1 ----
  const float4* fbase = (const float4*)(
      feats + ((size_t)(b * NC + tid) << 12) + (size_t)r0 * 64 + 32 * z);
  const float4 f0 = fbase[0], f1 = fbase[1], f2 = fbase[2], f3 = fbase[3];
  const float4 f4 = fbase[4], f5 = fbase[5], f6 = fbase[6], f7 = fbase[7];

  // ---- Phase 1 (R7-proven) ----
  int ylo = 4 * r0 - 2; if (ylo < 0) ylo = 0;
  int yhi = 4 * r0 + 5; if (yhi > NOUT - 1) yhi = NOUT - 1;
  const int xlo = z ? 126 : 0;  // 130-wide window covers all taps of this half
  const int npix = (yhi - ylo + 1) * 130;
  const int own_lo = 4 * r0;    // count ownership: y in [4r0,4r0+4), x-half z

  for (int i = tid; i < npix; i += 256) {
    const int x = xlo + i % 130;
    const int y = ylo + i / 130;
    const int lbl = masks[((size_t)b * NOUT + y) * NOUT + x];
    if ((unsigned)lbl < NK) {
      // src = 0.25*t - 0.375 (half-pixel 4x); taps j0, j0+1, clamped
      const int ry = y >> 2, py = y & 3;
      const int j0y = (py < 2) ? ry - 1 : ry;
      const float fy = (py == 0) ? 0.625f : (py == 1) ? 0.875f
                     : (py == 2) ? 0.125f : 0.375f;
      const int rx = x >> 2, px = x & 3;
      const int j0x = (px < 2) ? rx - 1 : rx;
      const float fx = (px == 0) ? 0.625f : (px == 1) ? 0.875f
                     : (px == 2) ? 0.125f : 0.375f;

      const int cx0 = (j0x < 0) ? 0 : j0x;
      const int cx1 = (j0x + 1 > NSRC - 1) ? NSRC - 1 : j0x + 1;
      const float wx0 = 1.f - fx, wx1 = fx;
      const int ry0 = (j0y < 0) ? 0 : j0y;
      const int ry1 = (j0y + 1 > NSRC - 1) ? NSRC - 1 : j0y + 1;
      const float wy0 = 1.f - fy, wy1 = fy;

      float* Wk = &Wl[lbl * 32];
      if (ry0 == r0) {
        if ((cx0 >> 5) == z) lds_fadd(&Wk[cx0 & 31], wy0 * wx0);
        if ((cx1 >> 5) == z) lds_fadd(&Wk[cx1 & 31], wy0 * wx1);
      }
      if (ry1 == r0) {
        if ((cx0 >> 5) == z) lds_fadd(&Wk[cx0 & 31], wy1 * wx0);
        if ((cx1 >> 5) == z) lds_fadd(&Wk[cx1 & 31], wy1 * wx1);
      }
      if (y >= own_lo && y < own_lo + 4 && (x >> 7) == z)
        atomicAdd(&hist[lbl], 1);  // int: native ds_add
    }
  }
  __syncthreads();  // drains mask loads + feats prefetch (hidden under phase 1)

  // ---- Phase 2: acc[k] = sum_s W[k][s] * F[s] ----
  float acc[NK];
#pragma unroll
  for (int k = 0; k < NK; ++k) acc[k] = 0.f;

  const float4* wb = (const float4*)Wl;
#pragma unroll
  for (int k = 0; k < NK; ++k) {  // s 0..15
    const float4 w0 = wb[k * 8 + 0], w1 = wb[k * 8 + 1];
    const float4 w2 = wb[k * 8 + 2], w3 = wb[k * 8 + 3];
    float a = acc[k];
    a = fmaf(f0.x, w0.x, a); a = fmaf(f0.y, w0.y, a);
    a = fmaf(f0.z, w0.z, a); a = fmaf(f0.w, w0.w, a);
    a = fmaf(f1.x, w1.x, a); a = fmaf(f1.y, w1.y, a);
    a = fmaf(f1.z, w1.z, a); a = fmaf(f1.w, w1.w, a);
    a = fmaf(f2.x, w2.x, a); a = fmaf(f2.y, w2.y, a);
    a = fmaf(f2.z, w2.z, a); a = fmaf(f2.w, w2.w, a);
    a = fmaf(f3.x, w3.x, a); a = fmaf(f3.y, w3.y, a);
    a = fmaf(f3.z, w3.z, a); a = fmaf(f3.w, w3.w, a);
    acc[k] = a;
  }
#pragma unroll
  for (int k = 0; k < NK; ++k) {  // s 16..31
    const float4 w4 = wb[k * 8 + 4], w5 = wb[k * 8 + 5];
    const float4 w6 = wb[k * 8 + 6], w7 = wb[k * 8 + 7];
    float a = acc[k];
    a = fmaf(f4.x, w4.x, a); a = fmaf(f4.y, w4.y, a);
    a = fmaf(f4.z, w4.z, a); a = fmaf(f4.w, w4.w, a);
    a = fmaf(f5.x, w5.x, a); a = fmaf(f5.y, w5.y, a);
    a = fmaf(f5.z, w5.z, a); a = fmaf(f5.w, w5.w, a);
    a = fmaf(f6.x, w6.x, a); a = fmaf(f6.y, w6.y, a);
    a = fmaf(f6.z, w6.z, a); a = fmaf(f6.w, w6.w, a);
    a = fmaf(f7.x, w7.x, a); a = fmaf(f7.y, w7.y, a);
    a = fmaf(f7.z, w7.z, a); a = fmaf(f7.w, w7.w, a);
    acc[k] = a;
  }

  // ---- Epilogue: plain coalesced stores ----
  const int sl = r0 * 2 + z;
  float* dst = psum + ((size_t)(b * NSL + sl) * NK) * NC + tid;
#pragma unroll
  for (int k = 0; k < NK; ++k) dst[k * NC] = acc[k];
  if (tid < NK) pcnt[(size_t)(b * NSL + sl) * NK + tid] = (float)hist[tid];
}

// ---------------------------------------------------------------------------
// Finalize: grid (NK, NB) = 168 blocks; reduce all 128 slices (L2-resident),
// then ONE atomic per (k,c,b) into out (43K atomics — trivial at the wall).
// ---------------------------------------------------------------------------
__global__ __launch_bounds__(256)
void proto_final(const float* __restrict__ psum,
                 const float* __restrict__ pcnt,
                 float* __restrict__ out) {
  const int k = blockIdx.x;   // 0..20
  const int b = blockIdx.y;   // 0..7
  const int c = threadIdx.x;  // 0..255
  float s0 = 0.f, s1 = 0.f, s2 = 0.f, s3 = 0.f, cnt = 0.f;
#pragma unroll
  for (int sl = 0; sl < NSL; sl += 4) {
    s0 += psum[((size_t)(b * NSL + sl + 0) * NK + k) * NC + c];
    s1 += psum[((size_t)(b * NSL + sl + 1) * NK + k) * NC + c];
    s2 += psum[((size_t)(b * NSL + sl + 2) * NK + k) * NC + c];
    s3 += psum[((size_t)(b * NSL + sl + 3) * NK + k) * NC + c];
    cnt += pcnt[(size_t)(b * NSL + sl + 0) * NK + k];
    cnt += pcnt[(size_t)(b * NSL + sl + 1) * NK + k];
    cnt += pcnt[(size_t)(b * NSL + sl + 2) * NK + k];
    cnt += pcnt[(size_t)(b * NSL + sl + 3) * NK + k];
  }
  const float v = ((s0 + s1) + (s2 + s3)) / (cnt + EPS) * 0.125f;
  glb_fadd(&out[k * NC + c], v);
}

extern "C" void kernel_launch(void* const* d_in, const int* in_sizes, int n_in,
                              void* d_out, int out_size, void* d_ws, size_t ws_size,
                              hipStream_t stream) {
  const float* feats = (const float*)d_in[0];
  const int* masks = (const int*)d_in[1];
  float* out = (float*)d_out;

  // ws: psum [8][128][21][256] (22 MB) | pcnt [8][128][21] (86 KB).
  // Fully written before read; no memsets; 2 graph nodes total.
  float* psum = (float*)d_ws;
  float* pcnt = psum + (size_t)NB * NSL * NK * NC;

  proto_main<<<dim3(64, NB, 2), 256, 0, stream>>>(feats, masks, psum, pcnt, out);
  proto_final<<<dim3(NK, NB), 256, 0, stream>>>(psum, pcnt, out);
}